// Round 7
// baseline (269.045 us; speedup 1.0000x reference)
//
#include <hip/hip_runtime.h>
#include <math.h>

#define LL 128
#define TT 11
#define NP 121            // T*T (y, y_prev) pairs
#define KK 7
#define GS 20             // sp group stride (floats); group g at [g*20 .. g*20+10], pad at +11
#define SPW 240           // 11 groups*20 + dummy slots 220..226
#define NSLOT 8           // LDS pane ring slots (panes i..i+4 live simultaneously)
#define ROWF 128          // floats per staged pane row (121 used, padded for addressing)

#define LOG2E 1.4426950408889634f
#define LN2   0.6931471805599453f
#define NEG2  (-10000.0f * LOG2E)   // ref NEG in base-2 domain
#define MASK2 (-1.0e9f)             // masked -> exp2 underflows to exactly 0

typedef const __attribute__((address_space(1))) unsigned int* gas_t;
typedef __attribute__((address_space(3)))       unsigned int* las_t;

__device__ __forceinline__ float fast_exp2(float x) { return __builtin_amdgcn_exp2f(x); }
__device__ __forceinline__ float fast_log2(float x) { return __builtin_amdgcn_logf(x); }
__device__ __forceinline__ float rfl(float x) {
    return __int_as_float(__builtin_amdgcn_readfirstlane(__float_as_int(x)));
}
__device__ __forceinline__ void cfence() { __builtin_amdgcn_wave_barrier(); }
// Waits until <=28 vmem ops outstanding: with the steady-state ring (panes
// i+1,i+2,i+3 in flight = 42 ops at step entry) this completes pane i+1 and
// leaves panes i+2/i+3 in flight -- fine-grained vmcnt, never a full drain.
#define VMWAIT28() asm volatile("s_waitcnt vmcnt(28)" ::: "memory")

// ONE WAVE PER CU (16 blocks x 64 threads): serial latency chain; sharing
// pipes between waves doubles step time (round-4 evidence).
//
// Round 5/6 evidence: the compiler refuses to keep a depth-4 register
// prefetch resident (VGPR_Count pinned at 60 even with (64,1) bounds), so
// every step ate an unhidden memory round-trip (~1500 cyc/step). This
// version stages score panes via __builtin_amdgcn_global_load_lds (async
// DMA, no destination VGPRs => cannot be sunk) into an 8-slot LDS ring,
// issuing pane i+4 during step i and waiting s_waitcnt vmcnt(28) at each
// step (panes i+2/i+3 stay in flight; pane i+1 guaranteed complete).
// Prefetch lead = 3 steps, under OUR control, not the scheduler's.
//
// Algebra unchanged from round 5 (absmax 0): base-2 log domain, wave-uniform
// normalizer C pipelined 2 steps back via readfirstlane, off-chain partial pp
// (6 older terms of step i+1) computed during step i; only ONE exp2 on the
// serial chain. Phase 2: lane sums its group yp from sp via 3x b128 reads.
// Single-wave LDS ops complete in order -> compiler-only fences.
__global__ __launch_bounds__(64, 1) void hscrf_fwd(const float* __restrict__ scores,
                                                   const int* __restrict__ mask,
                                                   float* __restrict__ out,
                                                   int n_batch)
{
    const int l = threadIdx.x;
    const int b = blockIdx.x;
    if (b >= n_batch) return;

    __shared__ __align__(64) float pane[NSLOT][KK][ROWF];   // 28 KB ring
    __shared__ __align__(64) float sp[SPW];

    const int o1  = l + 64;
    const int o1c = (o1 < NP) ? o1 : 0;          // clamp for address math only
    const int y0 = l / TT,   yp0 = l % TT;
    const int y1 = o1c / TT, yp1 = o1c % TT;
    const int e0 = yp0 * TT + y0;                // pane element [yp][y]
    const int e1 = yp1 * TT + y1;
    const int i0w = y0 * GS + yp0;               // phase-1 write slots
    const int i1w = (o1 < NP) ? (y1 * GS + yp1) : (220 + (l - 57));

    // Zero the pad slot (element 11) of each sp group for 3x b128 phase-2.
    if (l < TT) sp[l * GS + 11] = 0.0f;

    const int mb = mask[b];
    const float* sb = scores + (size_t)b * (size_t)(LL * LL * NP);

    // DMA pane i (= scores[j][i-1][:][:], j = i-7..i-1, clipped) into its
    // ring slot. Per row: 64-lane dword (elems 0..63) + 57-lane dword
    // (elems 64..120). The l<57 predicate is REQUIRED: it prevents reading
    // past the end of the tensor on the very last row (b=15, j=127, col=127).
    auto dma_pane = [&](int i) {
        const int slot = i & (NSLOT - 1);
        const int col  = i - 1;
#pragma unroll
        for (int k = 0; k < KK; ++k) {
            int j  = i - KK + k;
            int jc = j < 0 ? 0 : j;              // clipped like ref; masked via window
            const float* g = sb + (size_t)(jc * LL + col) * NP;
            las_t lrow = (las_t)&pane[slot][k][0];
            __builtin_amdgcn_global_load_lds((gas_t)(g + l), lrow, 4, 0, 0);
            if (l < 57)
                __builtin_amdgcn_global_load_lds((gas_t)(g + 64 + l), lrow + 64, 4, 0, 0);
        }
    };

    // Sliding alpha2 window: win?[k] = alpha2[i-7+k][yp?] during step i.
    float win0[KK], win1[KK];
#pragma unroll
    for (int k = 0; k < KK; ++k) { win0[k] = MASK2; win1[k] = MASK2; }
    float na0 = (yp0 == TT - 1) ? 0.0f : NEG2;   // alpha2 row 0 (start_id = 10)
    float na1 = (yp1 == TT - 1) ? 0.0f : NEG2;

    float C  = 0.0f;   // normalizer for current step  (alpha2[i-2][0])
    float Cn = 0.0f;   // normalizer for next step     (alpha2[i-1][0])
    float pp0 = 0.0f, pp1 = 0.0f;   // off-chain partials for current step
    float saved = 0.0f;

    // Prologue: fill panes 1..4 (56 ops), wait to 28 (panes 1,2 complete),
    // read step-1 chain scores (pane 1 row 6). pp for step 1 is 0 (all its
    // k=0..5 spans have j<0).
    dma_pane(1); dma_pane(2); dma_pane(3); dma_pane(4);
    VMWAIT28();
    float rc0 = pane[1][KK - 1][e0];
    float rc1 = pane[1][KK - 1][e1];

    for (int i = 1; i <= LL; ++i) {
        // ---- serial chain: registers only, no pane access ----
#pragma unroll
        for (int k = 0; k < KK - 1; ++k) { win0[k] = win0[k + 1]; win1[k] = win1[k + 1]; }
        win0[KK - 1] = na0;
        win1[KK - 1] = na1;

        const float g0 = fast_exp2(fmaf(rc0, LOG2E, win0[KK - 1]) - C);
        const float g1 = fast_exp2(fmaf(rc1, LOG2E, win1[KK - 1]) - C);
        sp[i0w] = pp0 + g0;
        sp[i1w] = pp1 + g1;

        cfence();   // order sp write -> sp read (DS pipe in-order per wave)

        // Phase-2 reads issued immediately (chain-critical).
        const float4 qa0 = *(const float4*)(sp + yp0 * GS);
        const float4 qb0 = *(const float4*)(sp + yp0 * GS + 4);
        const float4 qc0 = *(const float4*)(sp + yp0 * GS + 8);   // [8..11], pad=0
        const float4 qa1 = *(const float4*)(sp + yp1 * GS);
        const float4 qb1 = *(const float4*)(sp + yp1 * GS + 4);
        const float4 qc1 = *(const float4*)(sp + yp1 * GS + 8);

        // Pane i+1 guaranteed complete after this (panes i+2,i+3 in flight).
        VMWAIT28();

        // Keep the ring full: pane i+4 -> back to 42 outstanding.
        if (i + 4 <= LL) dma_pane(i + 4);

        // Pane i+1 fragment reads (independent; latency hidden by pp math).
        const float* pn = &pane[(i + 1) & (NSLOT - 1)][0][0];
        float nr0[KK], nr1[KK];
#pragma unroll
        for (int k = 0; k < KK; ++k) {
            nr0[k] = pn[k * ROWF + e0];
            nr1[k] = pn[k * ROWF + e1];
        }

        // Off-chain pp for step i+1 (alpha2[i-6..i-1] = win[1..6], norm Cn).
        // At i==LL this reads a stale slot; values finite and discarded.
        float t0 = 0.0f, t1 = 0.0f;
#pragma unroll
        for (int k = 0; k < KK - 1; ++k) {
            t0 += fast_exp2(fmaf(nr0[k], LOG2E, win0[k + 1]) - Cn);
            t1 += fast_exp2(fmaf(nr1[k], LOG2E, win1[k + 1]) - Cn);
        }
        pp0 = t0;
        pp1 = t1;
        rc0 = nr0[KK - 1];
        rc1 = nr1[KK - 1];

        // Phase-2 sums (12 values incl. zero pad).
        const float S0 = (((qa0.x + qa0.y) + (qa0.z + qa0.w)) +
                          ((qb0.x + qb0.y) + (qb0.z + qb0.w))) +
                         ((qc0.x + qc0.y) + (qc0.z + qc0.w));
        const float S1 = (((qa1.x + qa1.y) + (qa1.z + qa1.w)) +
                          ((qb1.x + qb1.y) + (qb1.z + qb1.w))) +
                         ((qc1.x + qc1.y) + (qc1.z + qc1.w));

        const float A0 = C + fast_log2(S0);      // alpha2[i][yp0]
        const float A1 = C + fast_log2(S1);      // alpha2[i][yp1]
        na0 = A0;
        na1 = A1;
        saved = (i == mb) ? A0 : saved;

        // Normalizer pipeline: lane 0 has yp0==0 -> rfl(A0) = alpha2[i][0].
        C  = Cn;
        Cn = rfl(A0);

        cfence();   // order phase-2 sp reads before next step's sp writes
    }

    if (l == TT - 2) {                           // lane 9: yp0 == stop_id = 9
        atomicAdd(out, saved * LN2);             // back to natural log
    }
}

extern "C" void kernel_launch(void* const* d_in, const int* in_sizes, int n_in,
                              void* d_out, int out_size, void* d_ws, size_t ws_size,
                              hipStream_t stream) {
    const float* scores = (const float*)d_in[0];
    const int*   mask   = (const int*)d_in[1];
    float* out = (float*)d_out;
    const int B = in_sizes[1];   // 16

    hipMemsetAsync(out, 0, sizeof(float) * out_size, stream);
    hscrf_fwd<<<B, 64, 0, stream>>>(scores, mask, out, B);   // one wave per CU
}

// Round 8
// 209.779 us; speedup vs baseline: 1.2825x; 1.2825x over previous
//
#include <hip/hip_runtime.h>
#include <math.h>

#define LL 128
#define TT 11
#define NP 121            // T*T (y, y_prev) pairs
#define KK 7
#define GS 20             // sp group stride (floats); group g at [g*20 .. g*20+10], pad at +11
#define SPW 240           // 11 groups*20 + dummy slots 220..226
#define NSLOT 8           // E-pane LDS ring slots
#define PANEF 1024        // floats per E pane: 128 pairs x 8

#define LOG2E 1.4426950408889634f
#define LN2   0.6931471805599453f
#define NEG2  (-10000.0f * LOG2E)   // ref NEG in base-2 domain
#define MASK2 (-1.0e9f)             // masked -> exp2 underflows to exactly 0

typedef const __attribute__((address_space(1))) unsigned int* gas_t;
typedef __attribute__((address_space(3)))       unsigned int* las_t;

__device__ __forceinline__ float fast_exp2(float x) { return __builtin_amdgcn_exp2f(x); }
__device__ __forceinline__ float fast_log2(float x) { return __builtin_amdgcn_logf(x); }
#if __has_builtin(__builtin_amdgcn_rcpf)
__device__ __forceinline__ float fast_rcp(float x) { return __builtin_amdgcn_rcpf(x); }
#else
__device__ __forceinline__ float fast_rcp(float x) { return 1.0f / x; }
#endif
__device__ __forceinline__ float rfl(float x) {
    return __int_as_float(__builtin_amdgcn_readfirstlane(__float_as_int(x)));
}
__device__ __forceinline__ void cfence() { __builtin_amdgcn_wave_barrier(); }
#define VMWAIT20() asm volatile("s_waitcnt vmcnt(20)" ::: "memory")
#define VMWAIT0()  asm volatile("s_waitcnt vmcnt(0)"  ::: "memory")

// ---------------------------------------------------------------------------
// Prep: E[b][i-1][o][k] = exp2(scores[b][j][i-1][yp][y] * LOG2E), j = i-7+k
// (0 when j<0 or o>=121 or k==7). o = y*11 + yp (the DP lane's pair index).
// Massively parallel; runs once per call before the DP.
// ---------------------------------------------------------------------------
__global__ __launch_bounds__(256) void hscrf_prep(const float* __restrict__ scores,
                                                  float* __restrict__ E,
                                                  int n_batch)
{
    const int idx = blockIdx.x * blockDim.x + threadIdx.x;   // (b, pi, o)
    if (idx >= n_batch * LL * 128) return;
    const int o  = idx & 127;
    const int pi = (idx >> 7) & (LL - 1);   // pi = i-1
    const int b  = idx >> 14;

    float vals[8];
#pragma unroll
    for (int k = 0; k < 8; ++k) vals[k] = 0.0f;

    if (o < NP) {
        const int y = o / TT, yp = o % TT;
        const float* sb = scores + (size_t)b * (size_t)(LL * LL * NP);
#pragma unroll
        for (int k = 0; k < KK; ++k) {
            const int j = (pi + 1) - KK + k;
            if (j >= 0) {
                const float sc = sb[((size_t)j * LL + pi) * NP + yp * TT + y];
                vals[k] = fast_exp2(sc * LOG2E);
            }
        }
    }
    float4* dst = (float4*)(E + (size_t)idx * 8);
    dst[0] = make_float4(vals[0], vals[1], vals[2], vals[3]);
    dst[1] = make_float4(vals[4], vals[5], vals[6], vals[7]);
}

// ---------------------------------------------------------------------------
// DP: one wave per CU. Linear-domain window W[k][yp] = exp2(alpha2[row]-C):
// phase 1 is 7 FMAs (E from the LDS ring), phase 2 is the usual sp round-trip
// add tree, then W' = shift*r with r = rcp(S(0)) -- ZERO transcendentals on
// the serial chain. C (running log2 scale) is maintained off-chain for the
// final readout. E panes stream in via 4x width-16 global_load_lds per pane
// (compiler-proof prefetch), lead 5 steps, s_waitcnt vmcnt(20) per step.
// ---------------------------------------------------------------------------
__global__ __launch_bounds__(64, 1) void hscrf_dp(const float* __restrict__ E,
                                                  const int* __restrict__ mask,
                                                  float* __restrict__ out,
                                                  int n_batch)
{
    const int l = threadIdx.x;
    const int b = blockIdx.x;
    if (b >= n_batch) return;

    __shared__ __align__(64) float ring[NSLOT][PANEF];   // 32 KB
    __shared__ __align__(64) float sp[SPW];

    const int o1  = l + 64;
    const int o1c = (o1 < NP) ? o1 : 0;
    const int y0 = l / TT,   yp0 = l % TT;
    const int y1 = o1c / TT, yp1 = o1c % TT;
    const int i0w = y0 * GS + yp0;                        // phase-1 write slots
    const int i1w = (o1 < NP) ? (y1 * GS + yp1) : (220 + (l - 57));

    if (l < TT) sp[l * GS + 11] = 0.0f;                   // zero pad slot for b128 phase-2

    const int mb = mask[b];
    const float* Ebase = E + (size_t)b * (size_t)(LL * PANEF);

    // DMA pane i (floats (i-1)*1024 .. +1023) into ring slot i&7.
    // 4 ops x (64 lanes x 16 B). LDS dest is wave-uniform; HW adds lane*16.
    auto dma_pane = [&](int i) {
        const int slot = i & (NSLOT - 1);
        const float* src = Ebase + (size_t)(i - 1) * PANEF;
#pragma unroll
        for (int m = 0; m < 4; ++m)
            __builtin_amdgcn_global_load_lds((gas_t)(src + m * 256 + l * 4),
                                             (las_t)&ring[slot][m * 256], 16, 0, 0);
    };

    // Linear-domain windows. Row 0: start state (yp==10) = 1, others 0
    // (= exp2(NEG) which underflows to 0 in fp32, same as the reference).
    float W0[KK], W1[KK];
#pragma unroll
    for (int k = 0; k < KK; ++k) { W0[k] = 0.0f; W1[k] = 0.0f; }
    W0[KK - 1] = (yp0 == TT - 1) ? 1.0f : 0.0f;
    W1[KK - 1] = (yp1 == TT - 1) ? 1.0f : 0.0f;

    float Cc = 0.0f;       // running log2 scale: alpha2[i][y] = Cc + log2(S_i(y))
    float saved = 0.0f;

    // Prologue: panes 1..6 in flight (24 ops); wait to 20 -> pane 1 complete.
    dma_pane(1); dma_pane(2); dma_pane(3);
    dma_pane(4); dma_pane(5); dma_pane(6);
    VMWAIT20();

    // E regs for the current step (pane 1).
    const float4* ep1 = (const float4*)&ring[1][0];
    float4 ea0 = ep1[l * 2], ea1 = ep1[l * 2 + 1];
    float4 eb0 = ep1[(l + 64) * 2], eb1 = ep1[(l + 64) * 2 + 1];

    auto body = [&](int i, bool main) {
        // ---- phase 1: 7 FMAs per pair (tree), sp write ----
        float p0 = fmaf(ea0.x, W0[0], ea0.y * W0[1]);
        float q0 = fmaf(ea0.z, W0[2], ea0.w * W0[3]);
        float u0 = fmaf(ea1.x, W0[4], ea1.y * W0[5]);
        float s0 = (p0 + q0) + fmaf(ea1.z, W0[6], u0);
        float p1 = fmaf(eb0.x, W1[0], eb0.y * W1[1]);
        float q1 = fmaf(eb0.z, W1[2], eb0.w * W1[3]);
        float u1 = fmaf(eb1.x, W1[4], eb1.y * W1[5]);
        float s1 = (p1 + q1) + fmaf(eb1.z, W1[6], u1);
        sp[i0w] = s0;
        sp[i1w] = s1;

        cfence();                      // DS pipe in-order per wave

        // ---- phase 2 reads (chain-critical) ----
        const float4 qa0 = *(const float4*)(sp + yp0 * GS);
        const float4 qb0 = *(const float4*)(sp + yp0 * GS + 4);
        const float4 qc0 = *(const float4*)(sp + yp0 * GS + 8);   // pad=0
        const float4 qa1 = *(const float4*)(sp + yp1 * GS);
        const float4 qb1 = *(const float4*)(sp + yp1 * GS + 4);
        const float4 qc1 = *(const float4*)(sp + yp1 * GS + 8);

        if (main) {
            dma_pane(i + 6);           // keep ring full (panes i+1..i+6 in flight)
            VMWAIT20();                // completes pane i+1; i+2..i+6 stay in flight
        }

        // ---- E for next step (latency hidden: needed only next iteration) ----
        const int ns = (i + 1) & (NSLOT - 1);
        const float4* ep = (const float4*)&ring[ns][0];
        const float4 na0 = ep[l * 2], na1 = ep[l * 2 + 1];
        const float4 nb0 = ep[(l + 64) * 2], nb1 = ep[(l + 64) * 2 + 1];

        // ---- phase-2 sums ----
        const float SA = (((qa0.x + qa0.y) + (qa0.z + qa0.w)) +
                          ((qb0.x + qb0.y) + (qb0.z + qb0.w))) +
                         ((qc0.x + qc0.y) + (qc0.z + qc0.w));
        const float SB = (((qa1.x + qa1.y) + (qa1.z + qa1.w)) +
                          ((qb1.x + qb1.y) + (qb1.z + qb1.w))) +
                         ((qc1.x + qc1.y) + (qc1.z + qc1.w));

        // ---- rescale: r = 1/S(0) (lane 0 has yp0==0) ----
        const float s0u = rfl(SA);
        const float r = fast_rcp(s0u);

        saved = (i == mb) ? Cc + fast_log2(SA) : saved;   // alpha2[i][yp0], off-chain
        Cc += fast_log2(s0u);                             // off-chain

#pragma unroll
        for (int k = 0; k < KK - 1; ++k) { W0[k] = W0[k + 1] * r; W1[k] = W1[k + 1] * r; }
        W0[KK - 1] = SA * r;
        W1[KK - 1] = SB * r;

        ea0 = na0; ea1 = na1; eb0 = nb0; eb1 = nb1;

        cfence();                      // order phase-2 reads before next sp writes
    };

    for (int i = 1; i <= LL - 6; ++i) body(i, true);
    VMWAIT0();                         // tail: all remaining panes complete
    for (int i = LL - 5; i <= LL; ++i) body(i, false);

    if (l == TT - 2) {                 // lane 9: yp0 == stop_id = 9
        atomicAdd(out, saved * LN2);   // back to natural log
    }
}

// ---------------------------------------------------------------------------
// Fallback (round-6 kernel, known-correct 80.7 us) if ws_size can't hold E.
// ---------------------------------------------------------------------------
__global__ __launch_bounds__(64, 1) void hscrf_fwd_fb(const float* __restrict__ scores,
                                                      const int* __restrict__ mask,
                                                      float* __restrict__ out,
                                                      int n_batch)
{
    const int l = threadIdx.x;
    const int b = blockIdx.x;
    if (b >= n_batch) return;

    __shared__ __align__(64) float sp[SPW];

    const int o1  = l + 64;
    const int o1c = (o1 < NP) ? o1 : 0;
    const int y0 = l / TT,   yp0 = l % TT;
    const int y1 = o1c / TT, yp1 = o1c % TT;
    const int e0 = yp0 * TT + y0;
    const int e1 = yp1 * TT + y1;
    const int i0w = y0 * GS + yp0;
    const int i1w = (o1 < NP) ? (y1 * GS + yp1) : (220 + (l - 57));

    if (l < TT) sp[l * GS + 11] = 0.0f;

    const int mb = mask[b];
    const float* sb = scores + (size_t)b * (size_t)(LL * LL * NP);

    float win0[KK], win1[KK];
#pragma unroll
    for (int k = 0; k < KK; ++k) { win0[k] = MASK2; win1[k] = MASK2; }
    float na0 = (yp0 == TT - 1) ? 0.0f : NEG2;
    float na1 = (yp1 == TT - 1) ? 0.0f : NEG2;

    float C  = 0.0f, Cn = 0.0f, pp0 = 0.0f, pp1 = 0.0f, saved = 0.0f;

    float cA0[KK], cA1[KK], cB0[KK], cB1[KK];
    float cC0[KK], cC1[KK], cD0[KK], cD1[KK];

    auto load_pane = [&](int i, float (&c0)[KK], float (&c1)[KK]) {
#pragma unroll
        for (int k = 0; k < KK; ++k) {
            int j = i - KK + k;
            int jc = j < 0 ? 0 : j;
            const size_t base = ((size_t)jc * LL + (size_t)(i - 1)) * NP;
            c0[k] = sb[base + e0];
            c1[k] = sb[base + e1];
        }
    };

    load_pane(1, cA0, cA1); load_pane(2, cB0, cB1);
    load_pane(3, cC0, cC1); load_pane(4, cD0, cD1);

    auto step = [&](int i, float (&c0)[KK], float (&c1)[KK],
                    float (&n0)[KK], float (&n1)[KK]) {
#pragma unroll
        for (int k = 0; k < KK - 1; ++k) { win0[k] = win0[k + 1]; win1[k] = win1[k + 1]; }
        win0[KK - 1] = na0;
        win1[KK - 1] = na1;

        const float g0 = fast_exp2(fmaf(c0[KK - 1], LOG2E, win0[KK - 1]) - C);
        const float g1 = fast_exp2(fmaf(c1[KK - 1], LOG2E, win1[KK - 1]) - C);
        sp[i0w] = pp0 + g0;
        sp[i1w] = pp1 + g1;

        if (i + 4 <= LL) load_pane(i + 4, c0, c1);

        cfence();

        const float4 qa0 = *(const float4*)(sp + yp0 * GS);
        const float4 qb0 = *(const float4*)(sp + yp0 * GS + 4);
        const float4 qc0 = *(const float4*)(sp + yp0 * GS + 8);
        const float4 qa1 = *(const float4*)(sp + yp1 * GS);
        const float4 qb1 = *(const float4*)(sp + yp1 * GS + 4);
        const float4 qc1 = *(const float4*)(sp + yp1 * GS + 8);

        float t0 = 0.0f, t1 = 0.0f;
#pragma unroll
        for (int k = 0; k < KK - 1; ++k) {
            t0 += fast_exp2(fmaf(n0[k], LOG2E, win0[k + 1]) - Cn);
            t1 += fast_exp2(fmaf(n1[k], LOG2E, win1[k + 1]) - Cn);
        }
        pp0 = t0; pp1 = t1;

        const float S0 = (((qa0.x + qa0.y) + (qa0.z + qa0.w)) +
                          ((qb0.x + qb0.y) + (qb0.z + qb0.w))) +
                         ((qc0.x + qc0.y) + (qc0.z + qc0.w));
        const float S1 = (((qa1.x + qa1.y) + (qa1.z + qa1.w)) +
                          ((qb1.x + qb1.y) + (qb1.z + qb1.w))) +
                         ((qc1.x + qc1.y) + (qc1.z + qc1.w));

        const float A0 = C + fast_log2(S0);
        const float A1 = C + fast_log2(S1);
        na0 = A0; na1 = A1;
        saved = (i == mb) ? A0 : saved;
        C  = Cn;
        Cn = rfl(A0);

        cfence();
    };

    for (int i = 1; i <= LL; i += 4) {
        step(i,     cA0, cA1, cB0, cB1);
        step(i + 1, cB0, cB1, cC0, cC1);
        step(i + 2, cC0, cC1, cD0, cD1);
        step(i + 3, cD0, cD1, cA0, cA1);
    }

    if (l == TT - 2) atomicAdd(out, saved * LN2);
}

extern "C" void kernel_launch(void* const* d_in, const int* in_sizes, int n_in,
                              void* d_out, int out_size, void* d_ws, size_t ws_size,
                              hipStream_t stream) {
    const float* scores = (const float*)d_in[0];
    const int*   mask   = (const int*)d_in[1];
    float* out = (float*)d_out;
    const int B = in_sizes[1];   // 16

    hipMemsetAsync(out, 0, sizeof(float) * out_size, stream);

    const size_t need = (size_t)B * LL * 128 * 8 * sizeof(float);   // 8.39 MB
    if (ws_size >= need) {
        float* E = (float*)d_ws;
        const int total = B * LL * 128;
        hscrf_prep<<<(total + 255) / 256, 256, 0, stream>>>(scores, E, B);
        hscrf_dp<<<B, 64, 0, stream>>>(E, mask, out, B);
    } else {
        hscrf_fwd_fb<<<B, 64, 0, stream>>>(scores, mask, out, B);
    }
}